// Round 19
// baseline (50.312 us; speedup 1.0000x reference)
//
#include <hip/hip_runtime.h>
#include <hip/hip_bf16.h>

// AlignmentLoss: loss = -(sum(tril(G,-1)*eq) / (sum(tril(eq,-1)) * ||tril(G,-1)||_F))
// with G = A A^T, A: 4096x1024 fp32, target: 4096 int32 (classes < 1000).
//
//   S1 = 0.5*(sum_c ||s_c||^2 - sum_i ||a_i||^2)
//   S2 = 0.5*(sum_c n_c^2 - N)
//   S3 = sum_{i>j} g_ij^2  (lower-triangle 256^2 tiles, masked Frobenius)
//   loss = -S1 / (S2 * sqrt(S3))
//
// R19 = R18 with ONE change: gram blocks 512 -> 1024 threads (16 waves,
// 4x4 wave grid, 64x64 per wave).  R15 counters showed Occupancy 29% /
// MfmaUtil 14% at 2 waves/SIMD -- the last untested axis is TLP on the
// counted-vmcnt structure (R4's waves-test was on the drain-0 loop where
// TLP can't help).  Boundary wait scales to vmcnt(4) (4 loads/thread/tile).

typedef __attribute__((ext_vector_type(8))) short short8;
typedef __attribute__((ext_vector_type(4))) float f32x4;

#define N_ROWS 4096
#define D_DIM  1024
#define N_CLS  1000
#define NTIL   136         // 16*17/2 lower-triangle 256^2 tiles
#define NKT    16          // 1024 / BK, BK = 64

__device__ __forceinline__ unsigned short f2bf(float f) {
  unsigned u = __float_as_uint(f);
  u += 0x7fffu + ((u >> 16) & 1u);   // round-to-nearest-even
  return (unsigned short)(u >> 16);
}

__device__ __forceinline__ void gload16(const short* g, const char* l) {
  __builtin_amdgcn_global_load_lds(
      (const __attribute__((address_space(1))) unsigned*)g,
      (__attribute__((address_space(3))) unsigned*)(void*)l, 16, 0, 0);
}

// ---------------------------------------------------------------------------
// kconv: A fp32 -> Ab bf16 + per-block fp64 row-norm partials.  512 x 256.
// ---------------------------------------------------------------------------
__global__ void __launch_bounds__(256) kconv(const float* __restrict__ A,
                                             short* __restrict__ Ab,
                                             double* __restrict__ rowp) {
  __shared__ double wr2[4];
  const int tid = threadIdx.x, lane = tid & 63, w = tid >> 6;
  const int row0 = blockIdx.x * 8;
  double ls = 0.0;
#pragma unroll
  for (int rr = 0; rr < 2; ++rr) {
    const int i = row0 + w * 2 + rr;
    const float4* src = (const float4*)(A + (size_t)i * D_DIM);
    short4* dst = (short4*)(Ab + (size_t)i * D_DIM);
    float s = 0.f;
#pragma unroll
    for (int c = 0; c < 4; ++c) {
      const float4 v = src[lane + c * 64];
      s += v.x * v.x + v.y * v.y + v.z * v.z + v.w * v.w;
      short4 o;
      o.x = (short)f2bf(v.x); o.y = (short)f2bf(v.y);
      o.z = (short)f2bf(v.z); o.w = (short)f2bf(v.w);
      dst[lane + c * 64] = o;
    }
#pragma unroll
    for (int off = 32; off; off >>= 1) s += __shfl_down(s, off);
    if (lane == 0) ls += (double)s;
  }
  if (lane == 0) wr2[w] = ls;
  __syncthreads();
  if (tid == 0) rowp[blockIdx.x] = wr2[0] + wr2[1] + wr2[2] + wr2[3];
}

// ---------------------------------------------------------------------------
// kmain: blocks 0..135 = 256^2 gram tile (1024 thr, 16 waves 4x4, 4-phase
//        counted-vmcnt); blocks 136.. = per-class reduction.
// ---------------------------------------------------------------------------
__global__ void __launch_bounds__(1024, 1) kmain(const float* __restrict__ A,
                                                 const int* __restrict__ target,
                                                 const short* __restrict__ Ab,
                                                 double* __restrict__ frobp,
                                                 double* __restrict__ cssp,
                                                 int* __restrict__ cntp) {
  __shared__ __align__(16) char smem[131072];   // 128 KB pool
  const int tid = threadIdx.x, lane = tid & 63, w = tid >> 6;

  if (blockIdx.x < NTIL) {
    // ---------------- gram tile ----------------
    // bijective XCD swizzle: 136 = 8 * 17
    const int b = (blockIdx.x & 7) * 17 + (blockIdx.x >> 3);
    int bi = (int)((sqrtf(8.f * (float)b + 1.f) - 1.f) * 0.5f);
    while ((bi + 1) * (bi + 2) / 2 <= b) ++bi;
    while (bi * (bi + 1) / 2 > b) --bi;
    const int bj = b - bi * (bi + 1) / 2;
    const bool diag = (bi == bj);

    const short* Pa = Ab + (size_t)(bi * 256) * D_DIM;
    const short* Pb = Ab + (size_t)(bj * 256) * D_DIM;

    // LDS: per buf per matrix 32 KB = [2 ksub][256 rows][64 B]
    short* const As0 = (short*)smem;
    short* const As1 = (short*)(smem + 32768);
    short* const Bs0 = (short*)(smem + 65536);
    short* const Bs1 = (short*)(smem + 98304);

    f32x4 acc[4][4];
#pragma unroll
    for (int m = 0; m < 4; ++m)
#pragma unroll
      for (int n = 0; n < 4; ++n) acc[m][n] = (f32x4){0.f, 0.f, 0.f, 0.f};

    const int wm = w >> 2, wn = w & 3;       // 4x4 wave grid: rows wm*64, cols wn*64
    const int row16 = lane & 15, ck = lane >> 4;

    // staging (1024 thr): 1 gload16/thread per (matrix, half).  ksub = tid>>9;
    // within-ksub: sr = (tid&511)>>2 (row 0..127), sc = tid&3 (chunk), swz.
    const int ksub = tid >> 9;
    const int sr = (tid & 511) >> 2;
    const int scS = (tid & 3) ^ ((sr >> 1) & 3);
    const int wl = (w & 7) * 1024;           // within-ksub wave LDS base

#define STAGEU(P, BUF, h, kt)                                               \
    gload16((P) + ((size_t)((h) * 128 + sr)) * D_DIM + (kt) * 64 + ksub * 32 + scS * 8, \
            (const char*)(BUF) + ksub * 16384 + (h) * 8192 + wl)

#define STAGET(AB, BB, kt)                                                  \
    do {                                                                    \
      STAGEU(Pa, AB, 0, kt); STAGEU(Pa, AB, 1, kt);                         \
      STAGEU(Pb, BB, 0, kt); STAGEU(Pb, BB, 1, kt);                         \
    } while (0)

#define RD_A(BUF, MH)                                                       \
    _Pragma("unroll") for (int ks = 0; ks < 2; ++ks)                        \
    _Pragma("unroll") for (int m = 0; m < 2; ++m) {                         \
      const int R = wm * 64 + ((MH) * 2 + m) * 16 + row16;                  \
      a[ks][m] = *(const short8*)((const char*)(BUF) + ks * 16384 + R * 64  \
                                  + ((ck ^ ((R >> 1) & 3)) << 4));          \
    }
#define RD_B(DST, BUF, NH)                                                  \
    _Pragma("unroll") for (int ks = 0; ks < 2; ++ks)                        \
    _Pragma("unroll") for (int n = 0; n < 2; ++n) {                         \
      const int R = wn * 64 + ((NH) * 2 + n) * 16 + row16;                  \
      DST[ks][n] = *(const short8*)((const char*)(BUF) + ks * 16384 + R * 64\
                                    + ((ck ^ ((R >> 1) & 3)) << 4));        \
    }
#define PH_MFMA(MO, NO, BB)                                                 \
    __builtin_amdgcn_s_setprio(1);                                          \
    _Pragma("unroll") for (int ks = 0; ks < 2; ++ks)                        \
    _Pragma("unroll") for (int m = 0; m < 2; ++m)                           \
    _Pragma("unroll") for (int n = 0; n < 2; ++n)                           \
      acc[(MO) + m][(NO) + n] = __builtin_amdgcn_mfma_f32_16x16x32_bf16(    \
          a[ks][m], BB[ks][n], acc[(MO) + m][(NO) + n], 0, 0, 0);           \
    __builtin_amdgcn_s_setprio(0);
#define BAR __builtin_amdgcn_s_barrier()
#define SBZ __builtin_amdgcn_sched_barrier(0)

    // prologue: T0 -> buf0, drain; T1 -> buf1 stays in flight
    STAGET(As0, Bs0, 0);
    asm volatile("s_waitcnt vmcnt(0)" ::: "memory");
    SBZ;
    BAR;
    STAGET(As1, Bs1, 1);

#pragma unroll 1
    for (int t = 0; t < NKT; ++t) {
      const int c = t & 1;
      short* const As = c ? As1 : As0;     // wave-uniform select
      short* const Bs = c ? Bs1 : Bs0;
      short8 a[2][2], bq0[2][2], b1[2][2];
      // ---- ph1: m01 x n01
      RD_A(As, 0); RD_B(bq0, Bs, 0);
      BAR;
      PH_MFMA(0, 0, bq0);
      BAR;
      // ---- ph2: m01 x n23
      RD_B(b1, Bs, 1);
      BAR;
      PH_MFMA(0, 2, b1);
      BAR;
      // ---- ph3: m23 x n23  (last reads of buf c)
      RD_A(As, 1);
      BAR;
      PH_MFMA(2, 2, b1);
      BAR;                          // all reads of buf c retired
      // ---- ph4: stage T(t+2) into buf c (now free); m23 x n01
      if (t + 2 < NKT) STAGET(As, Bs, t + 2);
      PH_MFMA(2, 0, bq0);
      // ---- boundary: T(t+1) resident; T(t+2)'s 4 loads stay in flight
      if (t + 2 < NKT) {
        asm volatile("s_waitcnt vmcnt(4)" ::: "memory");
      } else if (t + 1 < NKT) {
        asm volatile("s_waitcnt vmcnt(0)" ::: "memory");
      }
      SBZ;
      BAR;
    }
#undef STAGEU
#undef STAGET
#undef RD_A
#undef RD_B
#undef PH_MFMA
#undef BAR
#undef SBZ

    // epilogue: masked Frobenius
    float fs = 0.f;
    if (!diag) {
#pragma unroll
      for (int m = 0; m < 4; ++m)
#pragma unroll
        for (int n = 0; n < 4; ++n)
#pragma unroll
          for (int q = 0; q < 4; ++q) fs += acc[m][n][q] * acc[m][n][q];
    } else {
      const int rbase = (lane >> 4) * 4, cbase = lane & 15;
#pragma unroll
      for (int m = 0; m < 4; ++m)
#pragma unroll
        for (int n = 0; n < 4; ++n)
#pragma unroll
          for (int q = 0; q < 4; ++q) {
            const int rl = wm * 64 + m * 16 + rbase + q;
            const int cl = wn * 64 + n * 16 + cbase;
            if (rl > cl) fs += acc[m][n][q] * acc[m][n][q];
          }
    }
#pragma unroll
    for (int off = 32; off; off >>= 1) fs += __shfl_down(fs, off);
    double* wredd = (double*)smem;       // LDS free after the loop
    __syncthreads();
    if (lane == 0) wredd[w] = (double)fs;
    __syncthreads();
    if (tid == 0) {
      double t = 0.0;
#pragma unroll
      for (int i = 0; i < 16; ++i) t += wredd[i];
      frobp[b] = t;
    }
  } else {
    // ---------------- per-class reduction (1024 thr, 1 dim/thread) --------
    int* list = (int*)smem;                      // 16 KB
    int* lcnt = (int*)(smem + 16384);
    float* wredf = (float*)(smem + 16400);       // 16 floats
    const int c = blockIdx.x - NTIL;
    if (c >= N_CLS) return;
    if (tid == 0) *lcnt = 0;
    __syncthreads();
    for (int j = tid; j < N_ROWS; j += 1024)
      if (target[j] == c) { int p = atomicAdd(lcnt, 1); list[p] = j; }
    __syncthreads();
    const int n = *lcnt;
    float accv = 0.f;
    for (int m = 0; m < n; ++m)
      accv += A[(size_t)list[m] * D_DIM + tid];
    float s = accv * accv;
#pragma unroll
    for (int off = 32; off; off >>= 1) s += __shfl_down(s, off);
    if (lane == 0) wredf[w] = s;
    __syncthreads();
    if (tid == 0) {
      float t = 0.f;
#pragma unroll
      for (int i = 0; i < 16; ++i) t += wredf[i];
      cssp[c] = (double)t;
      cntp[c] = n;
    }
  }
}

// ---------------------------------------------------------------------------
// kfinal: fp64 reduce + scalar math.
// ---------------------------------------------------------------------------
__global__ void __launch_bounds__(256) kfinal(const double* __restrict__ rowp,
                                              const double* __restrict__ cssp,
                                              const int* __restrict__ cntp,
                                              const double* __restrict__ frobp,
                                              float* __restrict__ out) {
  __shared__ double red[256];
  const int tid = threadIdx.x;
  double lsum = rowp[tid] + rowp[tid + 256];
  double lcss = 0.0, lcnn = 0.0, lfr = 0.0;
  for (int c = tid; c < N_CLS; c += 256) {
    lcss += cssp[c];
    const double nc = (double)cntp[c];
    lcnn += nc * nc;
  }
  if (tid < NTIL) lfr = frobp[tid];

  double vals[4] = {lsum, lcss, lcnn, lfr};
  double res[4];
  for (int v = 0; v < 4; ++v) {
    red[tid] = vals[v];
    __syncthreads();
    for (int s = 128; s; s >>= 1) {
      if (tid < s) red[tid] += red[tid + s];
      __syncthreads();
    }
    res[v] = red[0];
    __syncthreads();
  }
  if (tid == 0) {
    const double sumr = res[0], css = res[1], cnn = res[2], frob = res[3];
    const double S1 = 0.5 * (css - sumr);
    const double S2 = 0.5 * (cnn - (double)N_ROWS);
    const double S3 = frob;
    out[0] = (float)(-(S1 / (S2 * sqrt(S3))));
  }
}

extern "C" void kernel_launch(void* const* d_in, const int* in_sizes, int n_in,
                              void* d_out, int out_size, void* d_ws, size_t ws_size,
                              hipStream_t stream) {
  const float* A = (const float*)d_in[0];
  const int* target = (const int*)d_in[1];
  float* out = (float*)d_out;

  char* ws = (char*)d_ws;
  short*  Ab    = (short*)ws;                                   // 8,388,608 B
  double* rowp  = (double*)(ws + 8388608);                      // 512 doubles
  double* cssp  = (double*)(ws + 8388608 + 4096);               // 1000 doubles
  int*    cntp  = (int*)   (ws + 8388608 + 4096 + 8000);        // 1000 ints (pad 4096)
  double* frobp = (double*)(ws + 8388608 + 4096 + 8000 + 4096); // 136 doubles

  kconv<<<512, 256, 0, stream>>>(A, Ab, rowp);
  kmain<<<NTIL + N_CLS, 1024, 0, stream>>>(A, target, Ab, frobp, cssp, cntp);
  kfinal<<<1, 256, 0, stream>>>(rowp, cssp, cntp, frobp, out);
}

// Round 20
// 45.534 us; speedup vs baseline: 1.1049x; 1.1049x over previous
//
#include <hip/hip_runtime.h>
#include <hip/hip_bf16.h>

// AlignmentLoss: loss = -(sum(tril(G,-1)*eq) / (sum(tril(eq,-1)) * ||tril(G,-1)||_F))
// with G = A A^T, A: 4096x1024 fp32, target: 4096 int32 (classes < 1000).
//
//   S1 = 0.5*(sum_c ||s_c||^2 - sum_i ||a_i||^2)   (exact fp32/fp64 path)
//   S2 = 0.5*(sum_c n_c^2 - N)
//   S3 = sum_{i>j} g_ij^2  -- lower-triangle 256x256 tiles, bf16 MFMA,
//        fused masked Frobenius.
//   loss = -S1 / (S2 * sqrt(S3))
//
// R20 = R12 verbatim (best measured: 45.5 us).  19 rounds of axis sweeps
// (schedule x waves x tile x depth x swizzle x FLOP-side x fusion) all land
// at 45-50 us; this configuration is the measured optimum.  Lock-in round.

typedef __attribute__((ext_vector_type(8))) short short8;
typedef __attribute__((ext_vector_type(4))) float f32x4;

#define N_ROWS 4096
#define D_DIM  1024
#define N_CLS  1000
#define NTIL   136         // 16*17/2 lower-triangle 256^2 tiles

__device__ __forceinline__ unsigned short f2bf(float f) {
  unsigned u = __float_as_uint(f);
  u += 0x7fffu + ((u >> 16) & 1u);   // round-to-nearest-even
  return (unsigned short)(u >> 16);
}

__device__ __forceinline__ void gload16(const short* g, const char* l) {
  __builtin_amdgcn_global_load_lds(
      (const __attribute__((address_space(1))) unsigned*)g,
      (__attribute__((address_space(3))) unsigned*)(void*)l, 16, 0, 0);
}

// ---------------------------------------------------------------------------
// kconv: A fp32 -> Ab bf16 + per-block fp64 partial of sum ||a_i||^2.
// ---------------------------------------------------------------------------
__global__ void __launch_bounds__(256) kconv(const float* __restrict__ A,
                                             short* __restrict__ Ab,
                                             double* __restrict__ rowp) {
  __shared__ double wr2[4];
  const int tid = threadIdx.x, lane = tid & 63, w = tid >> 6;
  const int row0 = blockIdx.x * 8;
  double ls = 0.0;
#pragma unroll
  for (int rr = 0; rr < 2; ++rr) {
    const int i = row0 + w * 2 + rr;
    const float4* src = (const float4*)(A + (size_t)i * D_DIM);
    short4* dst = (short4*)(Ab + (size_t)i * D_DIM);
    float s = 0.f;
#pragma unroll
    for (int c = 0; c < 4; ++c) {
      const float4 v = src[lane + c * 64];
      s += v.x * v.x + v.y * v.y + v.z * v.z + v.w * v.w;
      short4 o;
      o.x = (short)f2bf(v.x); o.y = (short)f2bf(v.y);
      o.z = (short)f2bf(v.z); o.w = (short)f2bf(v.w);
      dst[lane + c * 64] = o;
    }
#pragma unroll
    for (int off = 32; off; off >>= 1) s += __shfl_down(s, off);
    if (lane == 0) ls += (double)s;
  }
  if (lane == 0) wr2[w] = ls;
  __syncthreads();
  if (tid == 0) rowp[blockIdx.x] = wr2[0] + wr2[1] + wr2[2] + wr2[3];
}

// ---------------------------------------------------------------------------
// kmain: blocks 0..135 = 256^2 gram tile (8-phase); blocks 136.. = class.
// ---------------------------------------------------------------------------
__global__ void __launch_bounds__(512, 2) kmain(const float* __restrict__ A,
                                                const int* __restrict__ target,
                                                const short* __restrict__ Ab,
                                                double* __restrict__ frobp,
                                                double* __restrict__ cssp,
                                                int* __restrict__ cntp) {
  __shared__ __align__(16) char smem[131072];   // 128 KB pool
  const int tid = threadIdx.x, lane = tid & 63, w = tid >> 6;

  if (blockIdx.x < NTIL) {
    // ---------------- gram tile, 8-phase ----------------
    // bijective XCD swizzle: 136 = 8 * 17
    const int b = (blockIdx.x & 7) * 17 + (blockIdx.x >> 3);
    int bi = (int)((sqrtf(8.f * (float)b + 1.f) - 1.f) * 0.5f);
    while ((bi + 1) * (bi + 2) / 2 <= b) ++bi;
    while (bi * (bi + 1) / 2 > b) --bi;
    const int bj = b - bi * (bi + 1) / 2;
    const bool diag = (bi == bj);

    const short* Pa = Ab + (size_t)(bi * 256) * D_DIM;
    const short* Pb = Ab + (size_t)(bj * 256) * D_DIM;

    // LDS: per buf per matrix 32 KB = [2 ksub][256 rows][64 B]
    short* As0 = (short*)smem;
    short* As1 = (short*)(smem + 32768);
    short* Bs0 = (short*)(smem + 65536);
    short* Bs1 = (short*)(smem + 98304);

    f32x4 acc[8][4];
#pragma unroll
    for (int m = 0; m < 8; ++m)
#pragma unroll
      for (int n = 0; n < 4; ++n) acc[m][n] = (f32x4){0.f, 0.f, 0.f, 0.f};

    const int wm = w >> 2, wn = w & 3;       // wave: rows wm*128, cols wn*64
    const int row16 = lane & 15, ck = lane >> 4;

    // staging: unit = (matrix, half h, K-tile kt): 2 gload16/thread (16 KB)
    const int sr = tid >> 2;                 // 0..127
    const int scS = (tid & 3) ^ ((sr >> 1) & 3);

#define STAGEU(P, BUF, h, kt)                                               \
    do {                                                                    \
      const short* _g = (P) + ((size_t)((h) * 128 + sr)) * D_DIM + (kt) * 64 + scS * 8; \
      gload16(_g,      (const char*)(BUF) + (h) * 8192 + w * 1024);         \
      gload16(_g + 32, (const char*)(BUF) + 16384 + (h) * 8192 + w * 1024); \
    } while (0)

#define RD_A(BUF, MH)                                                       \
    _Pragma("unroll") for (int ks = 0; ks < 2; ++ks)                        \
    _Pragma("unroll") for (int m = 0; m < 4; ++m) {                         \
      const int R = wm * 128 + ((MH) * 4 + m) * 16 + row16;                 \
      a[ks][m] = *(const short8*)((const char*)(BUF) + ks * 16384 + R * 64  \
                                  + ((ck ^ ((R >> 1) & 3)) << 4));          \
    }
#define RD_B(DST, BUF, NH)                                                  \
    _Pragma("unroll") for (int ks = 0; ks < 2; ++ks)                        \
    _Pragma("unroll") for (int n = 0; n < 2; ++n) {                         \
      const int R = wn * 64 + ((NH) * 2 + n) * 16 + row16;                  \
      DST[ks][n] = *(const short8*)((const char*)(BUF) + ks * 16384 + R * 64\
                                    + ((ck ^ ((R >> 1) & 3)) << 4));        \
    }
#define PH_MFMA(MO, NO, BB)                                                 \
    __builtin_amdgcn_s_setprio(1);                                          \
    _Pragma("unroll") for (int ks = 0; ks < 2; ++ks)                        \
    _Pragma("unroll") for (int m = 0; m < 4; ++m)                           \
    _Pragma("unroll") for (int n = 0; n < 2; ++n)                           \
      acc[(MO) + m][(NO) + n] = __builtin_amdgcn_mfma_f32_16x16x32_bf16(    \
          a[ks][m], BB[ks][n], acc[(MO) + m][(NO) + n], 0, 0, 0);           \
    __builtin_amdgcn_s_setprio(0);
#define BAR __builtin_amdgcn_s_barrier()
#define VM0 asm volatile("s_waitcnt vmcnt(0)" ::: "memory")

    // prologue: K-tile 0 -> buf0
    STAGEU(Pa, As0, 0, 0); STAGEU(Pa, As0, 1, 0);
    STAGEU(Pb, Bs0, 0, 0); STAGEU(Pb, Bs0, 1, 0);
    VM0;
    BAR;

#pragma unroll 1
    for (int it = 0; it < 8; ++it) {
      const int t1 = 2 * it + 1, t2 = 2 * it + 2;
      short8 a[2][4], bq0[2][2], b[2][2];
      // ---- ph1: t0 q0 (buf0) ; stage A of t1 -> buf1
      RD_A(As0, 0); RD_B(bq0, Bs0, 0);
      STAGEU(Pa, As1, 0, t1); STAGEU(Pa, As1, 1, t1);
      BAR;
      PH_MFMA(0, 0, bq0);
      BAR;
      // ---- ph2: q1 ; stage B of t1 -> buf1
      RD_B(b, Bs0, 1);
      STAGEU(Pb, Bs1, 0, t1); STAGEU(Pb, Bs1, 1, t1);
      BAR;
      PH_MFMA(0, 2, b);
      BAR;
      // ---- ph3: q2
      RD_A(As0, 1);
      BAR;
      PH_MFMA(4, 2, b);
      BAR;
      // ---- ph4: q3 (no reads/stages)
      PH_MFMA(4, 0, bq0);
      BAR;
      VM0;                 // t1's units (staged ph1-2) resident everywhere
      BAR;
      // ---- ph5: t1 q0 (buf1) ; stage A of t2 -> buf0 (freed after ph4)
      RD_A(As1, 0); RD_B(bq0, Bs1, 0);
      if (it < 7) { STAGEU(Pa, As0, 0, t2); STAGEU(Pa, As0, 1, t2); }
      BAR;
      PH_MFMA(0, 0, bq0);
      BAR;
      // ---- ph6: q1 ; stage B of t2 -> buf0
      RD_B(b, Bs1, 1);
      if (it < 7) { STAGEU(Pb, Bs0, 0, t2); STAGEU(Pb, Bs0, 1, t2); }
      BAR;
      PH_MFMA(0, 2, b);
      BAR;
      // ---- ph7: q2
      RD_A(As1, 1);
      BAR;
      PH_MFMA(4, 2, b);
      BAR;
      // ---- ph8: q3
      PH_MFMA(4, 0, bq0);
      BAR;
      VM0;                 // t2's units (staged ph5-6) resident
      BAR;
    }
#undef STAGEU
#undef RD_A
#undef RD_B
#undef PH_MFMA
#undef BAR
#undef VM0

    // epilogue: masked Frobenius
    float fs = 0.f;
    if (!diag) {
#pragma unroll
      for (int m = 0; m < 8; ++m)
#pragma unroll
        for (int n = 0; n < 4; ++n)
#pragma unroll
          for (int q = 0; q < 4; ++q) fs += acc[m][n][q] * acc[m][n][q];
    } else {
      const int rbase = (lane >> 4) * 4, cbase = lane & 15;
#pragma unroll
      for (int m = 0; m < 8; ++m)
#pragma unroll
        for (int n = 0; n < 4; ++n)
#pragma unroll
          for (int q = 0; q < 4; ++q) {
            const int rl = wm * 128 + m * 16 + rbase + q;
            const int cl = wn * 64 + n * 16 + cbase;
            if (rl > cl) fs += acc[m][n][q] * acc[m][n][q];
          }
    }
#pragma unroll
    for (int off = 32; off; off >>= 1) fs += __shfl_down(fs, off);
    double* wredd = (double*)smem;       // LDS free after the loop
    if (lane == 0) wredd[w] = (double)fs;
    __syncthreads();
    if (tid == 0) {
      double t = 0.0;
#pragma unroll
      for (int i = 0; i < 8; ++i) t += wredd[i];
      frobp[b] = t;
    }
  } else {
    // ---------------- per-class reduction ----------------
    int* list = (int*)smem;                      // 16 KB
    int* lcnt = (int*)(smem + 16384);
    float* wredf = (float*)(smem + 16400);       // 8 floats
    const int c = blockIdx.x - NTIL;
    if (c >= N_CLS) return;
    if (tid == 0) *lcnt = 0;
    __syncthreads();
    for (int j = tid; j < N_ROWS; j += 512)
      if (target[j] == c) { int p = atomicAdd(lcnt, 1); list[p] = j; }
    __syncthreads();
    const int n = *lcnt;
    float2 acc = make_float2(0.f, 0.f);
    for (int m = 0; m < n; ++m) {
      const float2 v = *(const float2*)(A + (size_t)list[m] * D_DIM + tid * 2);
      acc.x += v.x; acc.y += v.y;
    }
    float s = acc.x * acc.x + acc.y * acc.y;
#pragma unroll
    for (int off = 32; off; off >>= 1) s += __shfl_down(s, off);
    if (lane == 0) wredf[w] = s;
    __syncthreads();
    if (tid == 0) {
      float t = 0.f;
#pragma unroll
      for (int i = 0; i < 8; ++i) t += wredf[i];
      cssp[c] = (double)t;
      cntp[c] = n;
    }
  }
}

// ---------------------------------------------------------------------------
// kfinal: fp64 reduce + scalar math.
// ---------------------------------------------------------------------------
__global__ void __launch_bounds__(256) kfinal(const double* __restrict__ rowp,
                                              const double* __restrict__ cssp,
                                              const int* __restrict__ cntp,
                                              const double* __restrict__ frobp,
                                              float* __restrict__ out) {
  __shared__ double red[256];
  const int tid = threadIdx.x;
  double lsum = rowp[tid] + rowp[tid + 256];
  double lcss = 0.0, lcnn = 0.0, lfr = 0.0;
  for (int c = tid; c < N_CLS; c += 256) {
    lcss += cssp[c];
    const double nc = (double)cntp[c];
    lcnn += nc * nc;
  }
  if (tid < NTIL) lfr = frobp[tid];

  double vals[4] = {lsum, lcss, lcnn, lfr};
  double res[4];
  for (int v = 0; v < 4; ++v) {
    red[tid] = vals[v];
    __syncthreads();
    for (int s = 128; s; s >>= 1) {
      if (tid < s) red[tid] += red[tid + s];
      __syncthreads();
    }
    res[v] = red[0];
    __syncthreads();
  }
  if (tid == 0) {
    const double sumr = res[0], css = res[1], cnn = res[2], frob = res[3];
    const double S1 = 0.5 * (css - sumr);
    const double S2 = 0.5 * (cnn - (double)N_ROWS);
    const double S3 = frob;
    out[0] = (float)(-(S1 / (S2 * sqrt(S3))));
  }
}

extern "C" void kernel_launch(void* const* d_in, const int* in_sizes, int n_in,
                              void* d_out, int out_size, void* d_ws, size_t ws_size,
                              hipStream_t stream) {
  const float* A = (const float*)d_in[0];
  const int* target = (const int*)d_in[1];
  float* out = (float*)d_out;

  char* ws = (char*)d_ws;
  short*  Ab    = (short*)ws;                                   // 8,388,608 B
  double* rowp  = (double*)(ws + 8388608);                      // 512 doubles
  double* cssp  = (double*)(ws + 8388608 + 4096);               // 1000 doubles
  int*    cntp  = (int*)   (ws + 8388608 + 4096 + 8000);        // 1000 ints (pad 4096)
  double* frobp = (double*)(ws + 8388608 + 4096 + 8000 + 4096); // 136 doubles

  kconv<<<512, 256, 0, stream>>>(A, Ab, rowp);
  kmain<<<NTIL + N_CLS, 512, 0, stream>>>(A, target, Ab, frobp, cssp, cntp);
  kfinal<<<1, 256, 0, stream>>>(rowp, cssp, cntp, frobp, out);
}